// Round 3
// baseline (548.637 us; speedup 1.0000x reference)
//
#include <hip/hip_runtime.h>

#define KOFF 27
#define MPAIR 100000
#define NPAIR (KOFF * MPAIR)       // 2,700,000
#define NOUT 400000
#define CIN 32
#define COUT 32
#define OVF_CAP 65536

// ---------- workspace layouts ----------
// New path (CAP = 16 or 12):
//   cnt     @ 0          : 400000*4 = 1,600,000
//   ovf_cnt @ 1,600,000  : 256 (padded)
//   ovf     @ 1,600,256  : 65536*4 = 262,144
//   per_slot@ 1,862,400  : 400000*CAP*64 bytes
#define O_OVFCNT  ((size_t)1600000)
#define O_OVF     ((size_t)1600256)
#define O_PSLOT   ((size_t)1862400)
#define WS_NEED_CAP(cap) (O_PSLOT + (size_t)NOUT * (cap) * 64)

// R2 fallback path:
#define R2_O_OVFCNT  ((size_t)1600000)
#define R2_O_OVF     ((size_t)1600256)
#define R2_O_BUCKET  ((size_t)1633280)                 // 400000*32*4
#define R2_O_PEROFF  ((size_t)52833280)                // 2.7M*32*2
#define R2_WS_NEED   ((size_t)225633280)
#define R2_CAP 32

__device__ __forceinline__ unsigned int bf16pair(float a, float b) {
    unsigned int ua = __float_as_uint(a), ub = __float_as_uint(b);
    ua = (ua + 0x7fffu + ((ua >> 16) & 1u)) >> 16;   // RNE
    ub = (ub + 0x7fffu + ((ub >> 16) & 1u)) >> 16;
    return ua | (ub << 16);
}

// =======================================================================
// NEW PATH: fused matvec + slot-scatter, then contiguous gather
// =======================================================================
template <int CAP>
__global__ __launch_bounds__(256) void matvec_scatter_kernel(
    const float* __restrict__ feats, const float* __restrict__ weight,
    const int* __restrict__ in_map, const int* __restrict__ out_map,
    int* __restrict__ cnt, unsigned short* __restrict__ per_slot,
    int* __restrict__ ovf_cnt, int* __restrict__ ovf)
{
    const int k = blockIdx.y;                 // wave-uniform
    const int m = blockIdx.x * 256 + threadIdx.x;
    if (m >= MPAIR) return;
    const int p = k * MPAIR + m;
    const int in_row = in_map[p];
    const int row    = out_map[p];

    // issue the slot-allocation atomic early; latency hides under the matvec
    const int pos = atomicAdd(&cnt[row], 1);

    const float4* frow = reinterpret_cast<const float4*>(feats + (size_t)in_row * CIN);
    float4 f4[8];
#pragma unroll
    for (int i = 0; i < 8; ++i) f4[i] = frow[i];
    const float* f = reinterpret_cast<const float*>(f4);

    float acc[COUT];
#pragma unroll
    for (int i = 0; i < COUT; ++i) acc[i] = 0.f;

    const float* wk = weight + (size_t)k * (CIN * COUT);
#pragma unroll
    for (int ci = 0; ci < CIN; ++ci) {
        const float fv = f[ci];
#pragma unroll
        for (int co = 0; co < COUT; ++co)
            acc[co] = fmaf(fv, wk[ci * COUT + co], acc[co]);
    }

    if (pos < CAP) {
        uint4 u[4];
#pragma unroll
        for (int j = 0; j < 4; ++j) {
            u[j].x = bf16pair(acc[8 * j + 0], acc[8 * j + 1]);
            u[j].y = bf16pair(acc[8 * j + 2], acc[8 * j + 3]);
            u[j].z = bf16pair(acc[8 * j + 4], acc[8 * j + 5]);
            u[j].w = bf16pair(acc[8 * j + 6], acc[8 * j + 7]);
        }
        uint4* dst = reinterpret_cast<uint4*>(
            per_slot + ((size_t)row * CAP + pos) * COUT);
#pragma unroll
        for (int j = 0; j < 4; ++j) dst[j] = u[j];   // one 64B contiguous store
    } else {
        int o = atomicAdd(ovf_cnt, 1);
        if (o < OVF_CAP) ovf[o] = p;
    }
}

template <int CAP>
__global__ __launch_bounds__(256) void gather_slots_kernel(
    const unsigned short* __restrict__ per_slot, const int* __restrict__ cnt,
    float* __restrict__ out)
{
    int gid = blockIdx.x * 256 + threadIdx.x;
    int row = gid >> 5;                  // 32-lane group per output row
    int lane = gid & 31;
    if (row >= NOUT) return;

    int n = min(cnt[row], CAP);
    const unsigned short* base = per_slot + (size_t)row * CAP * COUT + lane;

    float acc = 0.f;
    for (int s = 0; s < n; ++s) {
        unsigned short v = base[s * COUT];         // 64B contiguous per group
        acc += __uint_as_float(((unsigned int)v) << 16);
    }
    out[row * COUT + lane] = acc;        // plain coalesced store; zeros if n==0
}

// rare overflow pairs: recompute matvec, f32 atomics into out (after gather)
__global__ __launch_bounds__(256) void ovf_recompute_kernel(
    const float* __restrict__ feats, const float* __restrict__ weight,
    const int* __restrict__ in_map, const int* __restrict__ out_map,
    const int* __restrict__ ovf_cnt, const int* __restrict__ ovf,
    float* __restrict__ out)
{
    int n = min(*ovf_cnt, OVF_CAP);
    for (int i = blockIdx.x * blockDim.x + threadIdx.x; i < n * 32;
         i += gridDim.x * blockDim.x) {
        int idx = i >> 5, co = i & 31;
        int p = ovf[idx];
        int k = p / MPAIR;
        int in_row = in_map[p];
        int row = out_map[p];
        const float* f = feats + (size_t)in_row * CIN;
        const float* wk = weight + (size_t)k * (CIN * COUT);
        float acc = 0.f;
#pragma unroll
        for (int ci = 0; ci < CIN; ++ci)
            acc = fmaf(f[ci], wk[ci * COUT + co], acc);
        atomicAdd(&out[row * COUT + co], acc);
    }
}

// =======================================================================
// R2 FALLBACK PATH (bucket of pair ids + per_off round trip)
// =======================================================================
__global__ __launch_bounds__(256) void fill_kernel(
    const int* __restrict__ out_map, int* __restrict__ cnt,
    int* __restrict__ bucket, int* __restrict__ ovf_cnt, int* __restrict__ ovf)
{
    int p = blockIdx.x * 256 + threadIdx.x;
    if (p >= NPAIR) return;
    int row = out_map[p];
    int slot = atomicAdd(&cnt[row], 1);
    if (slot < R2_CAP) {
        bucket[row * R2_CAP + slot] = p;
    } else {
        int o = atomicAdd(ovf_cnt, 1);
        if (o < OVF_CAP) ovf[o] = p;
    }
}

__global__ __launch_bounds__(256) void matvec_kernel(
    const float* __restrict__ feats, const float* __restrict__ weight,
    const int* __restrict__ in_map, unsigned short* __restrict__ per_off)
{
    const int k = blockIdx.y;
    const int m = blockIdx.x * 256 + threadIdx.x;
    if (m >= MPAIR) return;
    const int p = k * MPAIR + m;
    const int in_row = in_map[p];

    const float4* frow = reinterpret_cast<const float4*>(feats + (size_t)in_row * CIN);
    float4 f4[8];
#pragma unroll
    for (int i = 0; i < 8; ++i) f4[i] = frow[i];
    const float* f = reinterpret_cast<const float*>(f4);

    float acc[COUT];
#pragma unroll
    for (int i = 0; i < COUT; ++i) acc[i] = 0.f;
    const float* wk = weight + (size_t)k * (CIN * COUT);
#pragma unroll
    for (int ci = 0; ci < CIN; ++ci) {
        const float fv = f[ci];
#pragma unroll
        for (int co = 0; co < COUT; ++co)
            acc[co] = fmaf(fv, wk[ci * COUT + co], acc[co]);
    }
    uint4 u[4];
#pragma unroll
    for (int j = 0; j < 4; ++j) {
        u[j].x = bf16pair(acc[8 * j + 0], acc[8 * j + 1]);
        u[j].y = bf16pair(acc[8 * j + 2], acc[8 * j + 3]);
        u[j].z = bf16pair(acc[8 * j + 4], acc[8 * j + 5]);
        u[j].w = bf16pair(acc[8 * j + 6], acc[8 * j + 7]);
    }
    uint4* dst = reinterpret_cast<uint4*>(per_off + (size_t)p * COUT);
#pragma unroll
    for (int j = 0; j < 4; ++j) dst[j] = u[j];
}

__global__ __launch_bounds__(256) void gather_kernel(
    const unsigned short* __restrict__ per_off, const int* __restrict__ cnt,
    const int* __restrict__ bucket, float* __restrict__ out)
{
    int gid = blockIdx.x * 256 + threadIdx.x;
    int row = gid >> 5;
    int lane = gid & 31;
    if (row >= NOUT) return;
    int n = min(cnt[row], R2_CAP);
    int pl = (lane < n) ? bucket[row * R2_CAP + lane] : 0;
    float acc = 0.f;
    for (int i = 0; i < n; ++i) {
        int pi = __shfl(pl, i, 32);
        unsigned short v = per_off[(size_t)pi * COUT + lane];
        acc += __uint_as_float(((unsigned int)v) << 16);
    }
    out[row * COUT + lane] = acc;
}

__global__ __launch_bounds__(256) void ovf_kernel(
    const unsigned short* __restrict__ per_off, const int* __restrict__ out_map,
    const int* __restrict__ ovf_cnt, const int* __restrict__ ovf,
    float* __restrict__ out)
{
    int n = min(*ovf_cnt, OVF_CAP);
    for (int i = blockIdx.x * blockDim.x + threadIdx.x; i < n * 32;
         i += gridDim.x * blockDim.x) {
        int idx = i >> 5, lane = i & 31;
        int p = ovf[idx];
        int row = out_map[p];
        float v = __uint_as_float(((unsigned int)per_off[(size_t)p * 32 + lane]) << 16);
        atomicAdd(&out[row * 32 + lane], v);
    }
}

// R1 last-resort fallback
__global__ __launch_bounds__(256) void spconvt_fallback(
    const float* __restrict__ feats, const float* __restrict__ weight,
    const int* __restrict__ in_map, const int* __restrict__ out_map,
    float* __restrict__ out)
{
    const int k = blockIdx.y;
    const int m = blockIdx.x * blockDim.x + threadIdx.x;
    const bool active = (m < MPAIR);
    const int mm = active ? m : (MPAIR - 1);
    const int pair = k * MPAIR + mm;
    const int in_row = in_map[pair];
    const int out_row = out_map[pair];
    const float4* frow = reinterpret_cast<const float4*>(feats + (size_t)in_row * CIN);
    float4 f4[8];
#pragma unroll
    for (int i = 0; i < 8; ++i) f4[i] = frow[i];
    const float* f = reinterpret_cast<const float*>(f4);
    float acc[COUT];
#pragma unroll
    for (int i = 0; i < COUT; ++i) acc[i] = 0.f;
    const float* wk = weight + (size_t)k * (CIN * COUT);
#pragma unroll
    for (int ci = 0; ci < CIN; ++ci) {
        const float fv = f[ci];
#pragma unroll
        for (int co = 0; co < COUT; ++co)
            acc[co] = fmaf(fv, wk[ci * COUT + co], acc[co]);
    }
    if (active) {
        float* orow = out + (size_t)out_row * COUT;
#pragma unroll
        for (int co = 0; co < COUT; ++co) atomicAdd(orow + co, acc[co]);
    }
}

// =======================================================================
template <int CAP>
static void launch_new_path(const float* feats, const float* weight,
                            const int* in_map, const int* out_map,
                            float* out, char* ws, hipStream_t stream) {
    int* cnt                 = (int*)(ws);
    int* ovf_cnt             = (int*)(ws + O_OVFCNT);
    int* ovf                 = (int*)(ws + O_OVF);
    unsigned short* per_slot = (unsigned short*)(ws + O_PSLOT);

    hipMemsetAsync(ws, 0, O_PSLOT, stream);   // cnt + ovf_cnt + ovf

    matvec_scatter_kernel<CAP><<<dim3((MPAIR + 255) / 256, KOFF), dim3(256), 0, stream>>>(
        feats, weight, in_map, out_map, cnt, per_slot, ovf_cnt, ovf);

    gather_slots_kernel<CAP><<<dim3((NOUT * 32) / 256), dim3(256), 0, stream>>>(
        per_slot, cnt, out);

    ovf_recompute_kernel<<<dim3(64), dim3(256), 0, stream>>>(
        feats, weight, in_map, out_map, ovf_cnt, ovf, out);
}

extern "C" void kernel_launch(void* const* d_in, const int* in_sizes, int n_in,
                              void* d_out, int out_size, void* d_ws, size_t ws_size,
                              hipStream_t stream) {
    const float* feats  = (const float*)d_in[0];
    const float* weight = (const float*)d_in[1];
    const int* in_map   = (const int*)d_in[2];
    const int* out_map  = (const int*)d_in[3];
    float* out          = (float*)d_out;
    char* ws            = (char*)d_ws;

    if (ws_size >= WS_NEED_CAP(16)) {
        launch_new_path<16>(feats, weight, in_map, out_map, out, ws, stream);
    } else if (ws_size >= WS_NEED_CAP(12)) {
        launch_new_path<12>(feats, weight, in_map, out_map, out, ws, stream);
    } else if (ws_size >= R2_WS_NEED) {
        int* cnt                = (int*)(ws);
        int* ovf_cnt            = (int*)(ws + R2_O_OVFCNT);
        int* ovf                = (int*)(ws + R2_O_OVF);
        int* bucket             = (int*)(ws + R2_O_BUCKET);
        unsigned short* per_off = (unsigned short*)(ws + R2_O_PEROFF);

        hipMemsetAsync(ws, 0, R2_O_BUCKET, stream);
        fill_kernel<<<dim3((NPAIR + 255) / 256), dim3(256), 0, stream>>>(
            out_map, cnt, bucket, ovf_cnt, ovf);
        matvec_kernel<<<dim3((MPAIR + 255) / 256, KOFF), dim3(256), 0, stream>>>(
            feats, weight, in_map, per_off);
        gather_kernel<<<dim3((NOUT * 32) / 256), dim3(256), 0, stream>>>(
            per_off, cnt, bucket, out);
        ovf_kernel<<<dim3(16), dim3(256), 0, stream>>>(
            per_off, out_map, ovf_cnt, ovf, out);
    } else {
        hipMemsetAsync(d_out, 0, (size_t)out_size * sizeof(float), stream);
        spconvt_fallback<<<dim3((MPAIR + 255) / 256, KOFF), dim3(256), 0, stream>>>(
            feats, weight, in_map, out_map, out);
    }
}

// Round 4
// 415.062 us; speedup vs baseline: 1.3218x; 1.3218x over previous
//
#include <hip/hip_runtime.h>

#define KOFF 27
#define MPAIR 100000
#define NPAIR (KOFF * MPAIR)       // 2,700,000
#define NOUT 400000
#define CIN 32
#define COUT 32
#define SLOTS 15                    // slots inline in 64B header record
#define OVF_CAP 65536

// ---------- workspace layout (bytes) ----------
// hdr     @ 0          : 400000 * 64        = 25,600,000   (int[16]: cnt + 15 slots)
// ovf_cnt @ 25,600,000 : 256 (padded)
// ovf     @ 25,600,256 : 65536*4            = 262,144
// per_off @ 25,862,400 : 2.7M * 32 * 2      = 172,800,000
// total = 198,662,400  (< proven-available 225,633,280)
#define O_OVFCNT  ((size_t)25600000)
#define O_OVF     ((size_t)25600256)
#define O_PEROFF  ((size_t)25862400)
#define WS_NEED   ((size_t)198662400)

__device__ __forceinline__ unsigned int bf16pair(float a, float b) {
    unsigned int ua = __float_as_uint(a), ub = __float_as_uint(b);
    ua = (ua + 0x7fffu + ((ua >> 16) & 1u)) >> 16;   // RNE
    ub = (ub + 0x7fffu + ((ub >> 16) & 1u)) >> 16;
    return ua | (ub << 16);
}

// ---------- Pass 1: fused matvec + inline-header slot scatter ----------
__global__ __launch_bounds__(256) void mvscatter_kernel(
    const float* __restrict__ feats, const float* __restrict__ weight,
    const int* __restrict__ in_map, const int* __restrict__ out_map,
    int* __restrict__ hdr, unsigned short* __restrict__ per_off,
    int* __restrict__ ovf_cnt, int* __restrict__ ovf)
{
    const int k = blockIdx.y;                 // wave-uniform -> scalar weights
    const int m = blockIdx.x * 256 + threadIdx.x;
    if (m >= MPAIR) return;
    const int p = k * MPAIR + m;
    const int in_row = in_map[p];
    const int row    = out_map[p];

    // slot allocation: atomic on word 0 of the 64B header record.
    // For pos<7 the subsequent slot write hits the SAME 32B sector.
    const int pos = atomicAdd(&hdr[row * 16], 1);

    const float4* frow = reinterpret_cast<const float4*>(feats + (size_t)in_row * CIN);
    float4 f4[8];
#pragma unroll
    for (int i = 0; i < 8; ++i) f4[i] = frow[i];
    const float* f = reinterpret_cast<const float*>(f4);

    float acc[COUT];
#pragma unroll
    for (int i = 0; i < COUT; ++i) acc[i] = 0.f;

    const float* wk = weight + (size_t)k * (CIN * COUT);
#pragma unroll
    for (int ci = 0; ci < CIN; ++ci) {
        const float fv = f[ci];
#pragma unroll
        for (int co = 0; co < COUT; ++co)
            acc[co] = fmaf(fv, wk[ci * COUT + co], acc[co]);
    }

    if (pos < SLOTS) {
        hdr[row * 16 + 1 + pos] = p;          // 4B scattered (often same sector as atomic)

        uint4 u[4];
#pragma unroll
        for (int j = 0; j < 4; ++j) {
            u[j].x = bf16pair(acc[8 * j + 0], acc[8 * j + 1]);
            u[j].y = bf16pair(acc[8 * j + 2], acc[8 * j + 3]);
            u[j].z = bf16pair(acc[8 * j + 4], acc[8 * j + 5]);
            u[j].w = bf16pair(acc[8 * j + 6], acc[8 * j + 7]);
        }
        uint4* dst = reinterpret_cast<uint4*>(per_off + (size_t)p * COUT);
#pragma unroll
        for (int j = 0; j < 4; ++j) dst[j] = u[j];   // 64B contiguous store
    } else {
        int o = atomicAdd(ovf_cnt, 1);
        if (o < OVF_CAP) ovf[o] = p;
    }
}

// ---------- Pass 2: gather (coalesced header, random 64B payload) ----------
__global__ __launch_bounds__(256) void gather_kernel(
    const unsigned short* __restrict__ per_off, const int* __restrict__ hdr,
    float* __restrict__ out)
{
    int gid = blockIdx.x * 256 + threadIdx.x;
    int row = gid >> 5;                  // 32-lane group per output row
    int lane = gid & 31;
    if (row >= NOUT) return;

    // 64B header read: lanes 0..15 fetch cnt + 15 slots, coalesced
    int h = (lane < 16) ? hdr[row * 16 + lane] : 0;
    int n = __shfl(h, 0, 32);
    n = min(n, SLOTS);

    float acc = 0.f;
    for (int i = 0; i < n; ++i) {
        int p = __shfl(h, 1 + i, 32);
        unsigned short v = per_off[(size_t)p * COUT + lane];   // 64B per group
        acc += __uint_as_float(((unsigned int)v) << 16);
    }
    out[row * COUT + lane] = acc;        // plain coalesced store; zeros if n==0
}

// ---------- Pass 3: rare overflow pairs, recompute + f32 atomics ----------
__global__ __launch_bounds__(256) void ovf_recompute_kernel(
    const float* __restrict__ feats, const float* __restrict__ weight,
    const int* __restrict__ in_map, const int* __restrict__ out_map,
    const int* __restrict__ ovf_cnt, const int* __restrict__ ovf,
    float* __restrict__ out)
{
    int n = min(*ovf_cnt, OVF_CAP);
    for (int i = blockIdx.x * blockDim.x + threadIdx.x; i < n * 32;
         i += gridDim.x * blockDim.x) {
        int idx = i >> 5, co = i & 31;
        int p = ovf[idx];
        int k = p / MPAIR;
        int in_row = in_map[p];
        int row = out_map[p];
        const float* f = feats + (size_t)in_row * CIN;
        const float* wk = weight + (size_t)k * (CIN * COUT);
        float acc = 0.f;
#pragma unroll
        for (int ci = 0; ci < CIN; ++ci)
            acc = fmaf(f[ci], wk[ci * COUT + co], acc);
        atomicAdd(&out[row * COUT + co], acc);
    }
}

// ---------- last-resort fallback (tiny ws): R1 atomic scatter ----------
__global__ __launch_bounds__(256) void spconvt_fallback(
    const float* __restrict__ feats, const float* __restrict__ weight,
    const int* __restrict__ in_map, const int* __restrict__ out_map,
    float* __restrict__ out)
{
    const int k = blockIdx.y;
    const int m = blockIdx.x * blockDim.x + threadIdx.x;
    const bool active = (m < MPAIR);
    const int mm = active ? m : (MPAIR - 1);
    const int pair = k * MPAIR + mm;
    const int in_row = in_map[pair];
    const int out_row = out_map[pair];
    const float4* frow = reinterpret_cast<const float4*>(feats + (size_t)in_row * CIN);
    float4 f4[8];
#pragma unroll
    for (int i = 0; i < 8; ++i) f4[i] = frow[i];
    const float* f = reinterpret_cast<const float*>(f4);
    float acc[COUT];
#pragma unroll
    for (int i = 0; i < COUT; ++i) acc[i] = 0.f;
    const float* wk = weight + (size_t)k * (CIN * COUT);
#pragma unroll
    for (int ci = 0; ci < CIN; ++ci) {
        const float fv = f[ci];
#pragma unroll
        for (int co = 0; co < COUT; ++co)
            acc[co] = fmaf(fv, wk[ci * COUT + co], acc[co]);
    }
    if (active) {
        float* orow = out + (size_t)out_row * COUT;
#pragma unroll
        for (int co = 0; co < COUT; ++co) atomicAdd(orow + co, acc[co]);
    }
}

extern "C" void kernel_launch(void* const* d_in, const int* in_sizes, int n_in,
                              void* d_out, int out_size, void* d_ws, size_t ws_size,
                              hipStream_t stream) {
    const float* feats  = (const float*)d_in[0];
    const float* weight = (const float*)d_in[1];
    const int* in_map   = (const int*)d_in[2];
    const int* out_map  = (const int*)d_in[3];
    float* out          = (float*)d_out;
    char* ws            = (char*)d_ws;

    if (ws_size >= WS_NEED) {
        int* hdr                = (int*)(ws);
        int* ovf_cnt            = (int*)(ws + O_OVFCNT);
        int* ovf                = (int*)(ws + O_OVF);
        unsigned short* per_off = (unsigned short*)(ws + O_PEROFF);

        // zero headers + ovf bookkeeping (25.9 MB, ~9 us)
        hipMemsetAsync(ws, 0, O_PEROFF, stream);

        mvscatter_kernel<<<dim3((MPAIR + 255) / 256, KOFF), dim3(256), 0, stream>>>(
            feats, weight, in_map, out_map, hdr, per_off, ovf_cnt, ovf);

        gather_kernel<<<dim3((NOUT * 32) / 256), dim3(256), 0, stream>>>(
            per_off, hdr, out);

        ovf_recompute_kernel<<<dim3(64), dim3(256), 0, stream>>>(
            feats, weight, in_map, out_map, ovf_cnt, ovf, out);
    } else {
        hipMemsetAsync(d_out, 0, (size_t)out_size * sizeof(float), stream);
        spconvt_fallback<<<dim3((MPAIR + 255) / 256, KOFF), dim3(256), 0, stream>>>(
            feats, weight, in_map, out_map, out);
    }
}